// Round 6
// baseline (715.649 us; speedup 1.0000x reference)
//
#include <hip/hip_runtime.h>
#include <hip/hip_bf16.h>

#define EDGES 1000000
#define NNODES 50000
#define NG 512
#define NTILES 15625  // EDGES/64
#define NCOLB 50176   // col-hist bins rounded to 196*256

typedef __attribute__((ext_vector_type(8))) short bf16x8;
typedef __attribute__((ext_vector_type(4))) float f32x4;

__device__ __forceinline__ unsigned short f2bf(float f){
  unsigned u = __float_as_uint(f);
  u += 0x7fffu + ((u >> 16) & 1u);
  return (unsigned short)(u >> 16);
}
__device__ __forceinline__ float bf2f(unsigned short h){
  return __uint_as_float(((unsigned)h) << 16);
}
__device__ __forceinline__ unsigned pk2bf(float x, float y){
  __hip_bfloat162 h = __float22bfloat162_rn(make_float2(x, y));
  union { __hip_bfloat162 h; unsigned u; } cv; cv.h = h;
  return cv.u;
}
// XCD-aware swizzle: contiguous tile ranges per XCD. TRUE BIJECTION:
// bid < nb8 (=nb&~7): (x,y)->(x*per+y), x in [0,8), y in [0,per) — bijective onto [0,nb8).
// bid >= nb8: identity (lands in [nb8,nb), disjoint from swizzled range).
__device__ __forceinline__ int xcd_swizzle(int bid, int nb){
  int nb8 = nb & ~7;
  if (bid >= nb8) return bid;
  int per = nb8 >> 3;
  return (bid & 7) * per + (bid >> 3);
}

// ---------------- prep: emb->bf16, W1->w1tn, W2->w2t ----------------
__global__ void prep_all(const float* __restrict__ emb, const float* __restrict__ W1,
                         const float* __restrict__ W2,
                         unsigned short* __restrict__ emb_bf,
                         unsigned short* __restrict__ w1tn, unsigned short* __restrict__ w2t){
  int i = blockIdx.x * 256 + threadIdx.x;
  if (i < NNODES * 64){
    emb_bf[i] = f2bf(emb[i]);
  } else {
    int j = i - NNODES * 64;
    if (j < 32768){
      int jj = j >> 6, k = j & 63;
      float v = (jj < 256) ? W1[k * 256 + jj] : W1[(k + 64) * 256 + (jj - 256)];
      w1tn[j] = f2bf(v);
    } else {
      int jj = j - 32768;
      if (jj < 16384){
        int n = jj >> 8, k = jj & 255;
        w2t[jj] = f2bf(W2[k * 64 + n]);
      }
    }
  }
}

// ---------------- per-graph edge counts (for mean denom) ----------------
__global__ void seg_hist(const int* __restrict__ ei, const int* __restrict__ batch,
                         unsigned* __restrict__ hist){
  __shared__ unsigned h[NG];
  int t = threadIdx.x;
  h[t] = 0; h[t + 256] = 0;
  __syncthreads();
  for (int i = 0; i < 4; i++){
    int e = blockIdx.x * 1024 + i * 256 + t;
    if (e < EDGES){
      int s = batch[ei[e]];
      atomicAdd(&h[s], 1u);
    }
  }
  __syncthreads();
  atomicAdd(&hist[t], h[t]);
  atomicAdd(&hist[t + 256], h[t + 256]);
}

// ---------------- counting sort by COL node (implies graph-sorted) ----------------
__global__ void col_hist(const int* __restrict__ ei, unsigned* __restrict__ chist){
  for (int i = 0; i < 4; i++){
    int e = blockIdx.x * 1024 + i * 256 + threadIdx.x;
    if (e < EDGES) atomicAdd(&chist[ei[e]], 1u);
  }
}

__global__ void col_scan1(const unsigned* __restrict__ chist, unsigned* __restrict__ cpre,
                          unsigned* __restrict__ bsum){
  __shared__ unsigned s[256];
  int t = threadIdx.x;
  int i = blockIdx.x * 256 + t;
  unsigned v = (i < NNODES) ? chist[i] : 0u;
  s[t] = v;
  __syncthreads();
  for (int o = 1; o < 256; o <<= 1){
    unsigned u = (t >= o) ? s[t - o] : 0u;
    __syncthreads();
    s[t] += u;
    __syncthreads();
  }
  cpre[i] = s[t] - v;                 // exclusive within block
  if (t == 255) bsum[blockIdx.x] = s[255];
}

__global__ void col_scan2(unsigned* __restrict__ bsum){   // 196 partials, 1 block
  __shared__ unsigned s[256];
  int t = threadIdx.x;
  unsigned v = (t < 196) ? bsum[t] : 0u;
  s[t] = v;
  __syncthreads();
  for (int o = 1; o < 256; o <<= 1){
    unsigned u = (t >= o) ? s[t - o] : 0u;
    __syncthreads();
    s[t] += u;
    __syncthreads();
  }
  if (t < 196) bsum[t] = s[t] - v;    // exclusive block offsets
}

__global__ void col_scan3(unsigned* __restrict__ cpre, const unsigned* __restrict__ bsum){
  int i = blockIdx.x * 256 + threadIdx.x;
  cpre[i] += bsum[blockIdx.x];
}

// emeta[pos] = (col, row, seg, orig_edge); cpre used as cursors (destructive)
__global__ void col_scatter(const int* __restrict__ ei, const int* __restrict__ batch,
                            unsigned* __restrict__ cpre, int4* __restrict__ emeta){
  for (int i = 0; i < 4; i++){
    int e = blockIdx.x * 1024 + i * 256 + threadIdx.x;
    if (e < EDGES){
      int cn = ei[e];
      int pos = (int)atomicAdd(&cpre[cn], 1u);
      emeta[pos] = make_int4(cn, ei[EDGES + e], batch[cn], e);
    }
  }
}

// ---------------- node GEMM: P[node][512] = emb @ [W1top | W1bot] ----------------
__global__ __launch_bounds__(256) void node_gemm(
    const unsigned short* __restrict__ emb_bf, const unsigned short* __restrict__ w1tn,
    unsigned short* __restrict__ P)
{
  __shared__ unsigned short As[64 * 72];   // 64 nodes x 64 k, +8 pad
  int t = threadIdx.x;
  int n0 = blockIdx.x * 64;
  {
    int nl = t >> 2, part = t & 3;
    int node = n0 + nl; if (node >= NNODES) node = 0;
    const int4* src = (const int4*)(emb_bf + node * 64 + part * 16);
    int4* dst = (int4*)(As + nl * 72 + part * 16);
    dst[0] = src[0]; dst[1] = src[1];
  }
  __syncthreads();
  int w = t >> 6, lane = t & 63, q = lane >> 4, c = lane & 15;
  f32x4 acc[4][8];
  for (int a = 0; a < 4; a++) for (int b = 0; b < 8; b++) for (int r = 0; r < 4; r++) acc[a][b][r] = 0.f;
  for (int k0 = 0; k0 < 64; k0 += 32){
    bf16x8 af[4];
    for (int tt = 0; tt < 4; tt++) af[tt] = *(const bf16x8*)(As + (tt * 16 + c) * 72 + k0 + q * 8);
    for (int n4 = 0; n4 < 8; n4++){
      bf16x8 bw = *(const bf16x8*)(w1tn + (w * 128 + n4 * 16 + c) * 64 + k0 + q * 8);
      for (int tt = 0; tt < 4; tt++)
        acc[tt][n4] = __builtin_amdgcn_mfma_f32_16x16x32_bf16(af[tt], bw, acc[tt][n4], 0, 0, 0);
    }
  }
  for (int tt = 0; tt < 4; tt++){
    for (int r = 0; r < 4; r++){
      int node = n0 + tt * 16 + q * 4 + r;
      if (node < NNODES){
        unsigned short* dst = P + (size_t)node * 512 + w * 128 + c;
        for (int n4 = 0; n4 < 8; n4++) dst[n4 * 16] = f2bf(acc[tt][n4][r]);
      }
    }
  }
}

// ---------------- K1: gather + segmented stats1 (deep prefetch) ----------------
__global__ __launch_bounds__(256) void k1_gather(
    const unsigned short* __restrict__ P, const int4* __restrict__ emeta,
    float* __restrict__ sum1, float* __restrict__ sqs1)
{
  int lane = threadIdx.x & 63;
  int bid = xcd_swizzle(blockIdx.x, gridDim.x);
  int wid = (bid * 256 + threadIdx.x) >> 6;
  if (wid >= NTILES) return;
  int p0 = wid * 64;
  int4 me = emeta[p0 + lane];
  int c4 = lane * 4;
  int s0 = __builtin_amdgcn_readlane(me.z, 0);
  bool uni = (__ballot(me.z == s0) == ~0ull);
  float sm0 = 0.f, sm1 = 0.f, sm2 = 0.f, sm3 = 0.f;
  float q0 = 0.f, q1 = 0.f, q2 = 0.f, q3 = 0.f;
  if (uni){
    int cprev = __builtin_amdgcn_readlane(me.x, 0);
    ushort4 a = *(const ushort4*)(P + (size_t)cprev * 512 + c4);
    #pragma unroll
    for (int eb = 0; eb < 64; eb += 16){
      ushort4 bb[16];
      #pragma unroll
      for (int j = 0; j < 16; j++){
        int re = __builtin_amdgcn_readlane(me.y, eb + j);
        bb[j] = *(const ushort4*)(P + (size_t)re * 512 + 256 + c4);
      }
      #pragma unroll
      for (int j = 0; j < 16; j++){
        int ce = __builtin_amdgcn_readlane(me.x, eb + j);
        if (ce != cprev){ a = *(const ushort4*)(P + (size_t)ce * 512 + c4); cprev = ce; }
        float x0 = bf2f(a.x) + bf2f(bb[j].x);
        float x1 = bf2f(a.y) + bf2f(bb[j].y);
        float x2v = bf2f(a.z) + bf2f(bb[j].z);
        float x3 = bf2f(a.w) + bf2f(bb[j].w);
        sm0 += x0; q0 += x0 * x0;
        sm1 += x1; q1 += x1 * x1;
        sm2 += x2v; q2 += x2v * x2v;
        sm3 += x3; q3 += x3 * x3;
      }
    }
    float* sp = sum1 + s0 * 256 + c4;
    float* qp = sqs1 + s0 * 256 + c4;
    atomicAdd(sp + 0, sm0); atomicAdd(sp + 1, sm1); atomicAdd(sp + 2, sm2); atomicAdd(sp + 3, sm3);
    atomicAdd(qp + 0, q0);  atomicAdd(qp + 1, q1);  atomicAdd(qp + 2, q2);  atomicAdd(qp + 3, q3);
  } else {
    int cur = s0;
    int cprev = -1;
    ushort4 a = make_ushort4(0,0,0,0);
    for (int e = 0; e < 64; e++){
      int ce = __builtin_amdgcn_readlane(me.x, e);
      int re = __builtin_amdgcn_readlane(me.y, e);
      if (ce != cprev){ a = *(const ushort4*)(P + (size_t)ce * 512 + c4); cprev = ce; }
      ushort4 b = *(const ushort4*)(P + (size_t)re * 512 + 256 + c4);
      int s = __builtin_amdgcn_readlane(me.z, e);
      if (s != cur){
        float* sp = sum1 + cur * 256 + c4;
        float* qp = sqs1 + cur * 256 + c4;
        atomicAdd(sp + 0, sm0); atomicAdd(sp + 1, sm1); atomicAdd(sp + 2, sm2); atomicAdd(sp + 3, sm3);
        atomicAdd(qp + 0, q0);  atomicAdd(qp + 1, q1);  atomicAdd(qp + 2, q2);  atomicAdd(qp + 3, q3);
        sm0 = sm1 = sm2 = sm3 = 0.f; q0 = q1 = q2 = q3 = 0.f;
        cur = s;
      }
      float x0 = bf2f(a.x) + bf2f(b.x);
      float x1 = bf2f(a.y) + bf2f(b.y);
      float x2v = bf2f(a.z) + bf2f(b.z);
      float x3 = bf2f(a.w) + bf2f(b.w);
      sm0 += x0; q0 += x0 * x0;
      sm1 += x1; q1 += x1 * x1;
      sm2 += x2v; q2 += x2v * x2v;
      sm3 += x3; q3 += x3 * x3;
    }
    float* sp = sum1 + cur * 256 + c4;
    float* qp = sqs1 + cur * 256 + c4;
    atomicAdd(sp + 0, sm0); atomicAdd(sp + 1, sm1); atomicAdd(sp + 2, sm2); atomicAdd(sp + 3, sm3);
    atomicAdd(qp + 0, q0);  atomicAdd(qp + 1, q1);  atomicAdd(qp + 2, q2);  atomicAdd(qp + 3, q3);
  }
}

// ---------------- finalize: emit rstd and mean*rstd ----------------
__global__ void finalize1(const float* __restrict__ sum1, const float* __restrict__ sqs1,
                          const unsigned* __restrict__ hist, float* __restrict__ r1,
                          float* __restrict__ mr1){
  int i = blockIdx.x * 256 + threadIdx.x;   // 512*256
  int g = i >> 8;
  float cnt = fmaxf((float)hist[g], 1.f);
  float m = sum1[i] / cnt;
  float v = sqs1[i] / cnt - m * m;
  v = fmaxf(v, 0.f);
  float r = rsqrtf(v + 1e-5f);
  r1[i] = r;
  mr1[i] = m * r;
}

__global__ void finalize2(const float* __restrict__ sum2, const float* __restrict__ sqs2,
                          const unsigned* __restrict__ hist, float* __restrict__ r2,
                          float* __restrict__ mr2){
  int i = blockIdx.x * 256 + threadIdx.x;   // 512*64
  int g = i >> 6;
  float cnt = fmaxf((float)hist[g], 1.f);
  float m = sum2[i] / cnt;
  float v = sqs2[i] / cnt - m * m;
  v = fmaxf(v, 0.f);
  float r = rsqrtf(v + 1e-5f);
  r2[i] = r;
  mr2[i] = m * r;
}

// ---------------- K2: gather -> norm/relu -> GEMM2 + stats2 + x2T store ----------------
__global__ __launch_bounds__(256) void k2_fused(
    const unsigned short* __restrict__ P, const unsigned short* __restrict__ w2t,
    const int4* __restrict__ emeta,
    const float* __restrict__ r1, const float* __restrict__ mr1,
    float* __restrict__ sum2, float* __restrict__ sqs2,
    unsigned short* __restrict__ x2t)
{
  __shared__ unsigned short Y[64 * 264];   // y1 tile, [edge][256ch] +8 pad
  __shared__ int segl[64];
  __shared__ short rsegA[64];
  __shared__ unsigned char rloA[65];
  __shared__ int nrunS;
  int t = threadIdx.x;
  int bid = xcd_swizzle(blockIdx.x, gridDim.x);
  int p0 = bid * 64;
  int w = t >> 6, lane = t & 63, q = lane >> 4, c = lane & 15;
  int c4 = lane * 4;
  int elb0 = w * 16;
  int4 me = emeta[p0 + elb0 + (lane & 15)];

  // deep prefetch: 16 outstanding row loads + first col + speculative-uniform stats
  ushort4 bb[16];
  #pragma unroll
  for (int e = 0; e < 16; e++){
    int re = __builtin_amdgcn_readlane(me.y, e);
    bb[e] = *(const ushort4*)(P + (size_t)re * 512 + 256 + c4);
  }
  int cprev = __builtin_amdgcn_readlane(me.x, 0);
  ushort4 a = *(const ushort4*)(P + (size_t)cprev * 512 + c4);
  int s0g = __builtin_amdgcn_readlane(me.z, 0);
  float4 r4  = *(const float4*)(r1  + s0g * 256 + c4);
  float4 mr4 = *(const float4*)(mr1 + s0g * 256 + c4);

  if (t < 64) segl[t] = emeta[p0 + t].z;
  if (w == 0){
    int sN = segl[lane];
    int nxt = (lane < 63) ? segl[lane + 1] : sN;
    unsigned long long mask = __ballot(sN != nxt);
    if (lane == 0){
      if (mask == 0ull){
        nrunS = 1; rloA[0] = 0; rloA[1] = 64; rsegA[0] = (short)sN;
      } else {
        int n = 0, cur = segl[0];
        rsegA[0] = (short)cur; rloA[0] = 0;
        for (int i = 1; i < 64; i++)
          if (segl[i] != cur){ cur = segl[i]; n++; rsegA[n] = (short)cur; rloA[n] = (unsigned char)i; }
        rloA[n + 1] = 64; nrunS = n + 1;
      }
    }
  }
  __syncthreads();
  int nrun = nrunS;
  bool uni = (nrun == 1);

  #pragma unroll
  for (int e = 0; e < 16; e++){
    int ce = __builtin_amdgcn_readlane(me.x, e);
    if (ce != cprev){ a = *(const ushort4*)(P + (size_t)ce * 512 + c4); cprev = ce; }
    float4 rr4 = r4, mm4 = mr4;
    if (!uni){
      int s = __builtin_amdgcn_readlane(me.z, e);
      rr4 = *(const float4*)(r1  + s * 256 + c4);
      mm4 = *(const float4*)(mr1 + s * 256 + c4);
    }
    float y0 = fmaxf(0.f, (bf2f(a.x) + bf2f(bb[e].x)) * rr4.x - mm4.x);
    float y1 = fmaxf(0.f, (bf2f(a.y) + bf2f(bb[e].y)) * rr4.y - mm4.y);
    float y2 = fmaxf(0.f, (bf2f(a.z) + bf2f(bb[e].z)) * rr4.z - mm4.z);
    float y3 = fmaxf(0.f, (bf2f(a.w) + bf2f(bb[e].w)) * rr4.w - mm4.w);
    uint2 pk;
    pk.x = pk2bf(y0, y1);
    pk.y = pk2bf(y2, y3);
    *(uint2*)(Y + (elb0 + e) * 264 + c4) = pk;
  }
  __syncthreads();

  // GEMM2: wave w owns out-channels [w*16, w*16+16)
  f32x4 acc2[4];
  for (int tt = 0; tt < 4; tt++) for (int r = 0; r < 4; r++) acc2[tt][r] = 0.f;
  int ch2 = w * 16 + c;
  for (int kc = 0; kc < 8; kc++){
    int k0 = kc * 32;
    bf16x8 bfr = *(const bf16x8*)(w2t + ch2 * 256 + k0 + q * 8);
    for (int tt = 0; tt < 4; tt++){
      bf16x8 afr = *(const bf16x8*)(Y + (tt * 16 + c) * 264 + k0 + q * 8);
      acc2[tt] = __builtin_amdgcn_mfma_f32_16x16x32_bf16(afr, bfr, acc2[tt], 0, 0, 0);
    }
  }

  if (uni){
    int s = segl[0];
    float sm = 0.f, sq = 0.f;
    for (int tt = 0; tt < 4; tt++)
      for (int r = 0; r < 4; r++){
        float v = acc2[tt][r];
        sm += v; sq += v * v;
      }
    sm += __shfl_xor(sm, 16); sq += __shfl_xor(sq, 16);
    sm += __shfl_xor(sm, 32); sq += __shfl_xor(sq, 32);
    if (q == 0){
      atomicAdd(&sum2[s * 64 + ch2], sm);
      atomicAdd(&sqs2[s * 64 + ch2], sq);
    }
  } else {
    for (int rr = 0; rr < nrun; rr++){
      int s = rsegA[rr], lo = rloA[rr], hi = rloA[rr + 1];
      float sm = 0.f, sq = 0.f;
      for (int tt = 0; tt < 4; tt++){
        int elb = tt * 16 + q * 4;
        for (int r = 0; r < 4; r++){
          int el = elb + r;
          if (el >= lo && el < hi){
            float v = acc2[tt][r];
            sm += v; sq += v * v;
          }
        }
      }
      sm += __shfl_xor(sm, 16); sq += __shfl_xor(sq, 16);
      sm += __shfl_xor(sm, 32); sq += __shfl_xor(sq, 32);
      if (q == 0){
        atomicAdd(&sum2[s * 64 + ch2], sm);
        atomicAdd(&sqs2[s * 64 + ch2], sq);
      }
    }
  }
  // x2T store: [ch][edge], ushort4 over 4 consecutive edges
  for (int tt = 0; tt < 4; tt++){
    uint2 pk;
    pk.x = pk2bf(acc2[tt][0], acc2[tt][1]);
    pk.y = pk2bf(acc2[tt][2], acc2[tt][3]);
    *(uint2*)(x2t + (size_t)ch2 * EDGES + p0 + tt * 16 + q * 4) = pk;
  }
}

// ---------------- K3: normalize2 + GEMV W3 (transposed x2) ----------------
__global__ __launch_bounds__(256) void k3_out(
    const unsigned short* __restrict__ x2t, const int4* __restrict__ emeta,
    const float* __restrict__ r2, const float* __restrict__ mr2,
    const float* __restrict__ W3, const float* __restrict__ b3, float* __restrict__ out)
{
  int pp = blockIdx.x * 256 + threadIdx.x;
  if (pp >= EDGES) return;
  int4 me = emeta[pp];
  const float* r2p  = r2  + me.z * 64;
  const float* mr2p = mr2 + me.z * 64;
  float acc = 0.f;
  #pragma unroll 8
  for (int ch = 0; ch < 64; ch++){
    float v = bf2f(x2t[(size_t)ch * EDGES + pp]);
    float y = fmaxf(0.f, v * r2p[ch] - mr2p[ch]);
    acc += y * W3[ch];
  }
  out[me.w] = acc + b3[0];
}

// ---------------- launch ----------------
extern "C" void kernel_launch(void* const* d_in, const int* in_sizes, int n_in,
                              void* d_out, int out_size, void* d_ws, size_t ws_size,
                              hipStream_t stream)
{
  (void)in_sizes; (void)n_in; (void)out_size;
  const float* emb = (const float*)d_in[0];
  const float* W1  = (const float*)d_in[1];
  const float* W2  = (const float*)d_in[3];
  const float* W3  = (const float*)d_in[5];
  const float* b3  = (const float*)d_in[6];
  const int* ei    = (const int*)d_in[7];
  const int* batch = (const int*)d_in[8];
  float* out = (float*)d_out;

  char* p = (char*)d_ws;
  size_t off = 0;
  auto take = [&](size_t n) -> char* {
    char* r = p + off;
    off += (n + 255) & ~(size_t)255;
    return r;
  };

  unsigned short* emb_bf = (unsigned short*)take((size_t)NNODES * 64 * 2);
  unsigned short* w1tn   = (unsigned short*)take(32768 * 2);
  unsigned short* w2t    = (unsigned short*)take(16384 * 2);
  int4* emeta = (int4*)take((size_t)EDGES * 16);
  unsigned short* P   = (unsigned short*)take((size_t)NNODES * 512 * 2);
  unsigned short* x2t = (unsigned short*)take((size_t)EDGES * 64 * 2);
  float* r1  = (float*)take(512 * 256 * 4);
  float* mr1 = (float*)take(512 * 256 * 4);
  float* r2  = (float*)take(512 * 64 * 4);
  float* mr2 = (float*)take(512 * 64 * 4);
  unsigned* cpre = (unsigned*)take(NCOLB * 4);
  unsigned* bsum = (unsigned*)take(256 * 4);
  // zero-init region (contiguous)
  char* zbase = p + off;
  unsigned* hist  = (unsigned*)take(NG * 4);
  unsigned* chist = (unsigned*)take(NCOLB * 4);
  float* sum1 = (float*)take(512 * 256 * 4);
  float* sqs1 = (float*)take(512 * 256 * 4);
  float* sum2 = (float*)take(512 * 64 * 4);
  float* sqs2 = (float*)take(512 * 64 * 4);
  size_t zsize = (size_t)((p + off) - zbase);

  if (ws_size < off) return;  // workspace too small — fail loudly via poison

  hipMemsetAsync(zbase, 0, zsize, stream);
  prep_all<<<12692, 256, 0, stream>>>(emb, W1, W2, emb_bf, w1tn, w2t);
  seg_hist<<<977, 256, 0, stream>>>(ei, batch, hist);
  col_hist<<<977, 256, 0, stream>>>(ei, chist);
  col_scan1<<<196, 256, 0, stream>>>(chist, cpre, bsum);
  col_scan2<<<1, 256, 0, stream>>>(bsum);
  col_scan3<<<196, 256, 0, stream>>>(cpre, bsum);
  col_scatter<<<977, 256, 0, stream>>>(ei, batch, cpre, emeta);
  node_gemm<<<(NNODES + 63) / 64, 256, 0, stream>>>(emb_bf, w1tn, P);
  k1_gather<<<(NTILES + 3) / 4, 256, 0, stream>>>(P, emeta, sum1, sqs1);
  finalize1<<<512, 256, 0, stream>>>(sum1, sqs1, hist, r1, mr1);
  k2_fused<<<NTILES, 256, 0, stream>>>(P, w2t, emeta, r1, mr1, sum2, sqs2, x2t);
  finalize2<<<128, 256, 0, stream>>>(sum2, sqs2, hist, r2, mr2);
  k3_out<<<3907, 256, 0, stream>>>(x2t, emeta, r2, mr2, W3, b3, out);
}

// Round 7
// 580.519 us; speedup vs baseline: 1.2328x; 1.2328x over previous
//
#include <hip/hip_runtime.h>
#include <hip/hip_bf16.h>

#define EDGES 1000000
#define NNODES 50000
#define NG 512
#define NTILES 15625  // EDGES/64
#define NCOLB 50176   // col-hist bins rounded to 196*256

typedef __attribute__((ext_vector_type(8))) short bf16x8;
typedef __attribute__((ext_vector_type(4))) float f32x4;

__device__ __forceinline__ unsigned short f2bf(float f){
  unsigned u = __float_as_uint(f);
  u += 0x7fffu + ((u >> 16) & 1u);
  return (unsigned short)(u >> 16);
}
__device__ __forceinline__ float bf2f(unsigned short h){
  return __uint_as_float(((unsigned)h) << 16);
}
__device__ __forceinline__ unsigned pk2bf(float x, float y){
  __hip_bfloat162 h = __float22bfloat162_rn(make_float2(x, y));
  union { __hip_bfloat162 h; unsigned u; } cv; cv.h = h;
  return cv.u;
}
// XCD-aware swizzle: contiguous tile ranges per XCD. TRUE BIJECTION:
// bid < nb8 (=nb&~7): (x,y)->(x*per+y), x in [0,8), y in [0,per) — bijective onto [0,nb8).
// bid >= nb8: identity (lands in [nb8,nb), disjoint from swizzled range).
__device__ __forceinline__ int xcd_swizzle(int bid, int nb){
  int nb8 = nb & ~7;
  if (bid >= nb8) return bid;
  int per = nb8 >> 3;
  return (bid & 7) * per + (bid >> 3);
}

// ---------------- prep: emb->bf16, W1->w1tn, W2->w2t ----------------
__global__ void prep_all(const float* __restrict__ emb, const float* __restrict__ W1,
                         const float* __restrict__ W2,
                         unsigned short* __restrict__ emb_bf,
                         unsigned short* __restrict__ w1tn, unsigned short* __restrict__ w2t){
  int i = blockIdx.x * 256 + threadIdx.x;
  if (i < NNODES * 64){
    emb_bf[i] = f2bf(emb[i]);
  } else {
    int j = i - NNODES * 64;
    if (j < 32768){
      int jj = j >> 6, k = j & 63;
      float v = (jj < 256) ? W1[k * 256 + jj] : W1[(k + 64) * 256 + (jj - 256)];
      w1tn[j] = f2bf(v);
    } else {
      int jj = j - 32768;
      if (jj < 16384){
        int n = jj >> 8, k = jj & 255;
        w2t[jj] = f2bf(W2[k * 64 + n]);
      }
    }
  }
}

// ---------------- per-graph edge counts (for mean denom) ----------------
__global__ void seg_hist(const int* __restrict__ ei, const int* __restrict__ batch,
                         unsigned* __restrict__ hist){
  __shared__ unsigned h[NG];
  int t = threadIdx.x;
  h[t] = 0; h[t + 256] = 0;
  __syncthreads();
  for (int i = 0; i < 4; i++){
    int e = blockIdx.x * 1024 + i * 256 + t;
    if (e < EDGES){
      int s = batch[ei[e]];
      atomicAdd(&h[s], 1u);
    }
  }
  __syncthreads();
  atomicAdd(&hist[t], h[t]);
  atomicAdd(&hist[t + 256], h[t + 256]);
}

// ---------------- counting sort by COL node (implies graph-sorted) ----------------
__global__ void col_hist(const int* __restrict__ ei, unsigned* __restrict__ chist){
  for (int i = 0; i < 4; i++){
    int e = blockIdx.x * 1024 + i * 256 + threadIdx.x;
    if (e < EDGES) atomicAdd(&chist[ei[e]], 1u);
  }
}

__global__ void col_scan1(const unsigned* __restrict__ chist, unsigned* __restrict__ cpre,
                          unsigned* __restrict__ bsum){
  __shared__ unsigned s[256];
  int t = threadIdx.x;
  int i = blockIdx.x * 256 + t;
  unsigned v = (i < NNODES) ? chist[i] : 0u;
  s[t] = v;
  __syncthreads();
  for (int o = 1; o < 256; o <<= 1){
    unsigned u = (t >= o) ? s[t - o] : 0u;
    __syncthreads();
    s[t] += u;
    __syncthreads();
  }
  cpre[i] = s[t] - v;                 // exclusive within block
  if (t == 255) bsum[blockIdx.x] = s[255];
}

__global__ void col_scan2(unsigned* __restrict__ bsum){   // 196 partials, 1 block
  __shared__ unsigned s[256];
  int t = threadIdx.x;
  unsigned v = (t < 196) ? bsum[t] : 0u;
  s[t] = v;
  __syncthreads();
  for (int o = 1; o < 256; o <<= 1){
    unsigned u = (t >= o) ? s[t - o] : 0u;
    __syncthreads();
    s[t] += u;
    __syncthreads();
  }
  if (t < 196) bsum[t] = s[t] - v;    // exclusive block offsets
}

__global__ void col_scan3(unsigned* __restrict__ cpre, const unsigned* __restrict__ bsum){
  int i = blockIdx.x * 256 + threadIdx.x;
  cpre[i] += bsum[blockIdx.x];
}

// emeta[pos] = (col, row, seg, orig_edge); cpre used as cursors (destructive)
__global__ void col_scatter(const int* __restrict__ ei, const int* __restrict__ batch,
                            unsigned* __restrict__ cpre, int4* __restrict__ emeta){
  for (int i = 0; i < 4; i++){
    int e = blockIdx.x * 1024 + i * 256 + threadIdx.x;
    if (e < EDGES){
      int cn = ei[e];
      int pos = (int)atomicAdd(&cpre[cn], 1u);
      emeta[pos] = make_int4(cn, ei[EDGES + e], batch[cn], e);
    }
  }
}

// ---------------- node GEMM: P[node][512] = emb @ [W1top | W1bot] ----------------
__global__ __launch_bounds__(256) void node_gemm(
    const unsigned short* __restrict__ emb_bf, const unsigned short* __restrict__ w1tn,
    unsigned short* __restrict__ P)
{
  __shared__ unsigned short As[64 * 72];   // 64 nodes x 64 k, +8 pad
  int t = threadIdx.x;
  int n0 = blockIdx.x * 64;
  {
    int nl = t >> 2, part = t & 3;
    int node = n0 + nl; if (node >= NNODES) node = 0;
    const int4* src = (const int4*)(emb_bf + node * 64 + part * 16);
    int4* dst = (int4*)(As + nl * 72 + part * 16);
    dst[0] = src[0]; dst[1] = src[1];
  }
  __syncthreads();
  int w = t >> 6, lane = t & 63, q = lane >> 4, c = lane & 15;
  f32x4 acc[4][8];
  for (int a = 0; a < 4; a++) for (int b = 0; b < 8; b++) for (int r = 0; r < 4; r++) acc[a][b][r] = 0.f;
  for (int k0 = 0; k0 < 64; k0 += 32){
    bf16x8 af[4];
    for (int tt = 0; tt < 4; tt++) af[tt] = *(const bf16x8*)(As + (tt * 16 + c) * 72 + k0 + q * 8);
    for (int n4 = 0; n4 < 8; n4++){
      bf16x8 bw = *(const bf16x8*)(w1tn + (w * 128 + n4 * 16 + c) * 64 + k0 + q * 8);
      for (int tt = 0; tt < 4; tt++)
        acc[tt][n4] = __builtin_amdgcn_mfma_f32_16x16x32_bf16(af[tt], bw, acc[tt][n4], 0, 0, 0);
    }
  }
  for (int tt = 0; tt < 4; tt++){
    for (int r = 0; r < 4; r++){
      int node = n0 + tt * 16 + q * 4 + r;
      if (node < NNODES){
        unsigned short* dst = P + (size_t)node * 512 + w * 128 + c;
        for (int n4 = 0; n4 < 8; n4++) dst[n4 * 16] = f2bf(acc[tt][n4][r]);
      }
    }
  }
}

// ---------------- K1: gather + segmented stats1 (R4 rolling prefetch — TLP-funded MLP) ----------------
__global__ __launch_bounds__(256) void k1_gather(
    const unsigned short* __restrict__ P, const int4* __restrict__ emeta,
    float* __restrict__ sum1, float* __restrict__ sqs1)
{
  int lane = threadIdx.x & 63;
  int bid = xcd_swizzle(blockIdx.x, gridDim.x);
  int wid = (bid * 256 + threadIdx.x) >> 6;
  if (wid >= NTILES) return;
  int p0 = wid * 64;
  int4 me = emeta[p0 + lane];
  int c4 = lane * 4;
  int s0 = __builtin_amdgcn_readlane(me.z, 0);
  bool uni = (__ballot(me.z == s0) == ~0ull);
  float sm0 = 0.f, sm1 = 0.f, sm2 = 0.f, sm3 = 0.f;
  float q0 = 0.f, q1 = 0.f, q2 = 0.f, q3 = 0.f;
  if (uni){
    int cprev = __builtin_amdgcn_readlane(me.x, 0);
    ushort4 a = *(const ushort4*)(P + (size_t)cprev * 512 + c4);
    ushort4 b = *(const ushort4*)(P + (size_t)__builtin_amdgcn_readlane(me.y, 0) * 512 + 256 + c4);
    #pragma unroll 4
    for (int e = 0; e < 64; e++){
      ushort4 bn = b;
      if (e < 63){
        int rn = __builtin_amdgcn_readlane(me.y, e + 1);
        bn = *(const ushort4*)(P + (size_t)rn * 512 + 256 + c4);
      }
      int ce = __builtin_amdgcn_readlane(me.x, e);
      if (ce != cprev){ a = *(const ushort4*)(P + (size_t)ce * 512 + c4); cprev = ce; }
      float x0 = bf2f(a.x) + bf2f(b.x);
      float x1 = bf2f(a.y) + bf2f(b.y);
      float x2v = bf2f(a.z) + bf2f(b.z);
      float x3 = bf2f(a.w) + bf2f(b.w);
      sm0 += x0; q0 += x0 * x0;
      sm1 += x1; q1 += x1 * x1;
      sm2 += x2v; q2 += x2v * x2v;
      sm3 += x3; q3 += x3 * x3;
      b = bn;
    }
    float* sp = sum1 + s0 * 256 + c4;
    float* qp = sqs1 + s0 * 256 + c4;
    atomicAdd(sp + 0, sm0); atomicAdd(sp + 1, sm1); atomicAdd(sp + 2, sm2); atomicAdd(sp + 3, sm3);
    atomicAdd(qp + 0, q0);  atomicAdd(qp + 1, q1);  atomicAdd(qp + 2, q2);  atomicAdd(qp + 3, q3);
  } else {
    int cur = s0;
    int cprev = -1;
    ushort4 a = make_ushort4(0,0,0,0);
    for (int e = 0; e < 64; e++){
      int ce = __builtin_amdgcn_readlane(me.x, e);
      int re = __builtin_amdgcn_readlane(me.y, e);
      if (ce != cprev){ a = *(const ushort4*)(P + (size_t)ce * 512 + c4); cprev = ce; }
      ushort4 b = *(const ushort4*)(P + (size_t)re * 512 + 256 + c4);
      int s = __builtin_amdgcn_readlane(me.z, e);
      if (s != cur){
        float* sp = sum1 + cur * 256 + c4;
        float* qp = sqs1 + cur * 256 + c4;
        atomicAdd(sp + 0, sm0); atomicAdd(sp + 1, sm1); atomicAdd(sp + 2, sm2); atomicAdd(sp + 3, sm3);
        atomicAdd(qp + 0, q0);  atomicAdd(qp + 1, q1);  atomicAdd(qp + 2, q2);  atomicAdd(qp + 3, q3);
        sm0 = sm1 = sm2 = sm3 = 0.f; q0 = q1 = q2 = q3 = 0.f;
        cur = s;
      }
      float x0 = bf2f(a.x) + bf2f(b.x);
      float x1 = bf2f(a.y) + bf2f(b.y);
      float x2v = bf2f(a.z) + bf2f(b.z);
      float x3 = bf2f(a.w) + bf2f(b.w);
      sm0 += x0; q0 += x0 * x0;
      sm1 += x1; q1 += x1 * x1;
      sm2 += x2v; q2 += x2v * x2v;
      sm3 += x3; q3 += x3 * x3;
    }
    float* sp = sum1 + cur * 256 + c4;
    float* qp = sqs1 + cur * 256 + c4;
    atomicAdd(sp + 0, sm0); atomicAdd(sp + 1, sm1); atomicAdd(sp + 2, sm2); atomicAdd(sp + 3, sm3);
    atomicAdd(qp + 0, q0);  atomicAdd(qp + 1, q1);  atomicAdd(qp + 2, q2);  atomicAdd(qp + 3, q3);
  }
}

// ---------------- finalize: emit rstd and mean*rstd ----------------
__global__ void finalize1(const float* __restrict__ sum1, const float* __restrict__ sqs1,
                          const unsigned* __restrict__ hist, float* __restrict__ r1,
                          float* __restrict__ mr1){
  int i = blockIdx.x * 256 + threadIdx.x;   // 512*256
  int g = i >> 8;
  float cnt = fmaxf((float)hist[g], 1.f);
  float m = sum1[i] / cnt;
  float v = sqs1[i] / cnt - m * m;
  v = fmaxf(v, 0.f);
  float r = rsqrtf(v + 1e-5f);
  r1[i] = r;
  mr1[i] = m * r;
}

__global__ void finalize2(const float* __restrict__ sum2, const float* __restrict__ sqs2,
                          const unsigned* __restrict__ hist, float* __restrict__ r2,
                          float* __restrict__ mr2){
  int i = blockIdx.x * 256 + threadIdx.x;   // 512*64
  int g = i >> 6;
  float cnt = fmaxf((float)hist[g], 1.f);
  float m = sum2[i] / cnt;
  float v = sqs2[i] / cnt - m * m;
  v = fmaxf(v, 0.f);
  float r = rsqrtf(v + 1e-5f);
  r2[i] = r;
  mr2[i] = m * r;
}

// ---------------- K2: gather -> norm/relu -> GEMM2 + stats2 + x2T store ----------------
__global__ __launch_bounds__(256) void k2_fused(
    const unsigned short* __restrict__ P, const unsigned short* __restrict__ w2t,
    const int4* __restrict__ emeta,
    const float* __restrict__ r1, const float* __restrict__ mr1,
    float* __restrict__ sum2, float* __restrict__ sqs2,
    unsigned short* __restrict__ x2t)
{
  __shared__ unsigned short Y[64 * 264];   // y1 tile, [edge][256ch] +8 pad
  __shared__ int segl[64];
  __shared__ short rsegA[64];
  __shared__ unsigned char rloA[65];
  __shared__ int nrunS;
  int t = threadIdx.x;
  int bid = xcd_swizzle(blockIdx.x, gridDim.x);
  int p0 = bid * 64;
  int w = t >> 6, lane = t & 63, q = lane >> 4, c = lane & 15;
  int c4 = lane * 4;
  int elb0 = w * 16;
  int4 me = emeta[p0 + elb0 + (lane & 15)];

  // deep prefetch: 16 outstanding row loads (k2 is LDS-occupancy-capped; VGPRs are free here)
  ushort4 bb[16];
  #pragma unroll
  for (int e = 0; e < 16; e++){
    int re = __builtin_amdgcn_readlane(me.y, e);
    bb[e] = *(const ushort4*)(P + (size_t)re * 512 + 256 + c4);
  }
  int cprev = __builtin_amdgcn_readlane(me.x, 0);
  ushort4 a = *(const ushort4*)(P + (size_t)cprev * 512 + c4);
  int s0g = __builtin_amdgcn_readlane(me.z, 0);
  float4 r4  = *(const float4*)(r1  + s0g * 256 + c4);
  float4 mr4 = *(const float4*)(mr1 + s0g * 256 + c4);

  if (t < 64) segl[t] = emeta[p0 + t].z;
  if (w == 0){
    int sN = segl[lane];
    int nxt = (lane < 63) ? segl[lane + 1] : sN;
    unsigned long long mask = __ballot(sN != nxt);
    if (lane == 0){
      if (mask == 0ull){
        nrunS = 1; rloA[0] = 0; rloA[1] = 64; rsegA[0] = (short)sN;
      } else {
        int n = 0, cur = segl[0];
        rsegA[0] = (short)cur; rloA[0] = 0;
        for (int i = 1; i < 64; i++)
          if (segl[i] != cur){ cur = segl[i]; n++; rsegA[n] = (short)cur; rloA[n] = (unsigned char)i; }
        rloA[n + 1] = 64; nrunS = n + 1;
      }
    }
  }
  __syncthreads();
  int nrun = nrunS;
  bool uni = (nrun == 1);

  #pragma unroll
  for (int e = 0; e < 16; e++){
    int ce = __builtin_amdgcn_readlane(me.x, e);
    if (ce != cprev){ a = *(const ushort4*)(P + (size_t)ce * 512 + c4); cprev = ce; }
    float4 rr4 = r4, mm4 = mr4;
    if (!uni){
      int s = __builtin_amdgcn_readlane(me.z, e);
      rr4 = *(const float4*)(r1  + s * 256 + c4);
      mm4 = *(const float4*)(mr1 + s * 256 + c4);
    }
    float y0 = fmaxf(0.f, (bf2f(a.x) + bf2f(bb[e].x)) * rr4.x - mm4.x);
    float y1 = fmaxf(0.f, (bf2f(a.y) + bf2f(bb[e].y)) * rr4.y - mm4.y);
    float y2 = fmaxf(0.f, (bf2f(a.z) + bf2f(bb[e].z)) * rr4.z - mm4.z);
    float y3 = fmaxf(0.f, (bf2f(a.w) + bf2f(bb[e].w)) * rr4.w - mm4.w);
    uint2 pk;
    pk.x = pk2bf(y0, y1);
    pk.y = pk2bf(y2, y3);
    *(uint2*)(Y + (elb0 + e) * 264 + c4) = pk;
  }
  __syncthreads();

  // GEMM2: wave w owns out-channels [w*16, w*16+16)
  f32x4 acc2[4];
  for (int tt = 0; tt < 4; tt++) for (int r = 0; r < 4; r++) acc2[tt][r] = 0.f;
  int ch2 = w * 16 + c;
  for (int kc = 0; kc < 8; kc++){
    int k0 = kc * 32;
    bf16x8 bfr = *(const bf16x8*)(w2t + ch2 * 256 + k0 + q * 8);
    for (int tt = 0; tt < 4; tt++){
      bf16x8 afr = *(const bf16x8*)(Y + (tt * 16 + c) * 264 + k0 + q * 8);
      acc2[tt] = __builtin_amdgcn_mfma_f32_16x16x32_bf16(afr, bfr, acc2[tt], 0, 0, 0);
    }
  }

  if (uni){
    int s = segl[0];
    float sm = 0.f, sq = 0.f;
    for (int tt = 0; tt < 4; tt++)
      for (int r = 0; r < 4; r++){
        float v = acc2[tt][r];
        sm += v; sq += v * v;
      }
    sm += __shfl_xor(sm, 16); sq += __shfl_xor(sq, 16);
    sm += __shfl_xor(sm, 32); sq += __shfl_xor(sq, 32);
    if (q == 0){
      atomicAdd(&sum2[s * 64 + ch2], sm);
      atomicAdd(&sqs2[s * 64 + ch2], sq);
    }
  } else {
    for (int rr = 0; rr < nrun; rr++){
      int s = rsegA[rr], lo = rloA[rr], hi = rloA[rr + 1];
      float sm = 0.f, sq = 0.f;
      for (int tt = 0; tt < 4; tt++){
        int elb = tt * 16 + q * 4;
        for (int r = 0; r < 4; r++){
          int el = elb + r;
          if (el >= lo && el < hi){
            float v = acc2[tt][r];
            sm += v; sq += v * v;
          }
        }
      }
      sm += __shfl_xor(sm, 16); sq += __shfl_xor(sq, 16);
      sm += __shfl_xor(sm, 32); sq += __shfl_xor(sq, 32);
      if (q == 0){
        atomicAdd(&sum2[s * 64 + ch2], sm);
        atomicAdd(&sqs2[s * 64 + ch2], sq);
      }
    }
  }
  // x2T store: [ch][edge], ushort4 over 4 consecutive edges
  for (int tt = 0; tt < 4; tt++){
    uint2 pk;
    pk.x = pk2bf(acc2[tt][0], acc2[tt][1]);
    pk.y = pk2bf(acc2[tt][2], acc2[tt][3]);
    *(uint2*)(x2t + (size_t)ch2 * EDGES + p0 + tt * 16 + q * 4) = pk;
  }
}

// ---------------- K3: normalize2 + GEMV W3 (transposed x2) ----------------
__global__ __launch_bounds__(256) void k3_out(
    const unsigned short* __restrict__ x2t, const int4* __restrict__ emeta,
    const float* __restrict__ r2, const float* __restrict__ mr2,
    const float* __restrict__ W3, const float* __restrict__ b3, float* __restrict__ out)
{
  int pp = blockIdx.x * 256 + threadIdx.x;
  if (pp >= EDGES) return;
  int4 me = emeta[pp];
  const float* r2p  = r2  + me.z * 64;
  const float* mr2p = mr2 + me.z * 64;
  float acc = 0.f;
  #pragma unroll 8
  for (int ch = 0; ch < 64; ch++){
    float v = bf2f(x2t[(size_t)ch * EDGES + pp]);
    float y = fmaxf(0.f, v * r2p[ch] - mr2p[ch]);
    acc += y * W3[ch];
  }
  out[me.w] = acc + b3[0];
}

// ---------------- launch ----------------
extern "C" void kernel_launch(void* const* d_in, const int* in_sizes, int n_in,
                              void* d_out, int out_size, void* d_ws, size_t ws_size,
                              hipStream_t stream)
{
  (void)in_sizes; (void)n_in; (void)out_size;
  const float* emb = (const float*)d_in[0];
  const float* W1  = (const float*)d_in[1];
  const float* W2  = (const float*)d_in[3];
  const float* W3  = (const float*)d_in[5];
  const float* b3  = (const float*)d_in[6];
  const int* ei    = (const int*)d_in[7];
  const int* batch = (const int*)d_in[8];
  float* out = (float*)d_out;

  char* p = (char*)d_ws;
  size_t off = 0;
  auto take = [&](size_t n) -> char* {
    char* r = p + off;
    off += (n + 255) & ~(size_t)255;
    return r;
  };

  unsigned short* emb_bf = (unsigned short*)take((size_t)NNODES * 64 * 2);
  unsigned short* w1tn   = (unsigned short*)take(32768 * 2);
  unsigned short* w2t    = (unsigned short*)take(16384 * 2);
  int4* emeta = (int4*)take((size_t)EDGES * 16);
  unsigned short* P   = (unsigned short*)take((size_t)NNODES * 512 * 2);
  unsigned short* x2t = (unsigned short*)take((size_t)EDGES * 64 * 2);
  float* r1  = (float*)take(512 * 256 * 4);
  float* mr1 = (float*)take(512 * 256 * 4);
  float* r2  = (float*)take(512 * 64 * 4);
  float* mr2 = (float*)take(512 * 64 * 4);
  unsigned* cpre = (unsigned*)take(NCOLB * 4);
  unsigned* bsum = (unsigned*)take(256 * 4);
  // zero-init region (contiguous)
  char* zbase = p + off;
  unsigned* hist  = (unsigned*)take(NG * 4);
  unsigned* chist = (unsigned*)take(NCOLB * 4);
  float* sum1 = (float*)take(512 * 256 * 4);
  float* sqs1 = (float*)take(512 * 256 * 4);
  float* sum2 = (float*)take(512 * 64 * 4);
  float* sqs2 = (float*)take(512 * 64 * 4);
  size_t zsize = (size_t)((p + off) - zbase);

  if (ws_size < off) return;  // workspace too small — fail loudly via poison

  hipMemsetAsync(zbase, 0, zsize, stream);
  prep_all<<<12692, 256, 0, stream>>>(emb, W1, W2, emb_bf, w1tn, w2t);
  seg_hist<<<977, 256, 0, stream>>>(ei, batch, hist);
  col_hist<<<977, 256, 0, stream>>>(ei, chist);
  col_scan1<<<196, 256, 0, stream>>>(chist, cpre, bsum);
  col_scan2<<<1, 256, 0, stream>>>(bsum);
  col_scan3<<<196, 256, 0, stream>>>(cpre, bsum);
  col_scatter<<<977, 256, 0, stream>>>(ei, batch, cpre, emeta);
  node_gemm<<<(NNODES + 63) / 64, 256, 0, stream>>>(emb_bf, w1tn, P);
  k1_gather<<<(NTILES + 3) / 4, 256, 0, stream>>>(P, emeta, sum1, sqs1);
  finalize1<<<512, 256, 0, stream>>>(sum1, sqs1, hist, r1, mr1);
  k2_fused<<<NTILES, 256, 0, stream>>>(P, w2t, emeta, r1, mr1, sum2, sqs2, x2t);
  finalize2<<<128, 256, 0, stream>>>(sum2, sqs2, hist, r2, mr2);
  k3_out<<<3907, 256, 0, stream>>>(x2t, emeta, r2, mr2, W3, b3, out);
}

// Round 8
// 575.571 us; speedup vs baseline: 1.2434x; 1.0086x over previous
//
#include <hip/hip_runtime.h>
#include <hip/hip_bf16.h>

#define EDGES 1000000
#define NNODES 50000
#define NG 512
#define NTILES 15625  // EDGES/64
#define NCOLB 50176   // col-hist bins rounded to 196*256

typedef __attribute__((ext_vector_type(8))) short bf16x8;
typedef __attribute__((ext_vector_type(4))) float f32x4;

__device__ __forceinline__ unsigned short f2bf(float f){
  unsigned u = __float_as_uint(f);
  u += 0x7fffu + ((u >> 16) & 1u);
  return (unsigned short)(u >> 16);
}
__device__ __forceinline__ float bf2f(unsigned short h){
  return __uint_as_float(((unsigned)h) << 16);
}
__device__ __forceinline__ unsigned pk2bf(float x, float y){
  __hip_bfloat162 h = __float22bfloat162_rn(make_float2(x, y));
  union { __hip_bfloat162 h; unsigned u; } cv; cv.h = h;
  return cv.u;
}
// XCD-aware swizzle: contiguous tile ranges per XCD. TRUE BIJECTION (see R5 post-mortem).
__device__ __forceinline__ int xcd_swizzle(int bid, int nb){
  int nb8 = nb & ~7;
  if (bid >= nb8) return bid;
  int per = nb8 >> 3;
  return (bid & 7) * per + (bid >> 3);
}

// ---------------- prep: emb->bf16, W1->w1tn, W2->w2t ----------------
__global__ void prep_all(const float* __restrict__ emb, const float* __restrict__ W1,
                         const float* __restrict__ W2,
                         unsigned short* __restrict__ emb_bf,
                         unsigned short* __restrict__ w1tn, unsigned short* __restrict__ w2t){
  int i = blockIdx.x * 256 + threadIdx.x;
  if (i < NNODES * 64){
    emb_bf[i] = f2bf(emb[i]);
  } else {
    int j = i - NNODES * 64;
    if (j < 32768){
      int jj = j >> 6, k = j & 63;
      float v = (jj < 256) ? W1[k * 256 + jj] : W1[(k + 64) * 256 + (jj - 256)];
      w1tn[j] = f2bf(v);
    } else {
      int jj = j - 32768;
      if (jj < 16384){
        int n = jj >> 8, k = jj & 255;
        w2t[jj] = f2bf(W2[k * 64 + n]);
      }
    }
  }
}

// ---------------- merged hists: per-graph counts (LDS-privatized) + per-col counts ----------------
__global__ void hists(const int* __restrict__ ei, const int* __restrict__ batch,
                      unsigned* __restrict__ hist, unsigned* __restrict__ chist){
  __shared__ unsigned h[NG];
  int t = threadIdx.x;
  h[t] = 0; h[t + 256] = 0;
  __syncthreads();
  for (int i = 0; i < 4; i++){
    int e = blockIdx.x * 1024 + i * 256 + t;
    if (e < EDGES){
      int cn = ei[e];
      atomicAdd(&chist[cn], 1u);
      atomicAdd(&h[batch[cn]], 1u);
    }
  }
  __syncthreads();
  atomicAdd(&hist[t], h[t]);
  atomicAdd(&hist[t + 256], h[t + 256]);
}

__global__ void col_scan1(const unsigned* __restrict__ chist, unsigned* __restrict__ cpre,
                          unsigned* __restrict__ bsum){
  __shared__ unsigned s[256];
  int t = threadIdx.x;
  int i = blockIdx.x * 256 + t;
  unsigned v = (i < NNODES) ? chist[i] : 0u;
  s[t] = v;
  __syncthreads();
  for (int o = 1; o < 256; o <<= 1){
    unsigned u = (t >= o) ? s[t - o] : 0u;
    __syncthreads();
    s[t] += u;
    __syncthreads();
  }
  cpre[i] = s[t] - v;                 // exclusive within block
  if (t == 255) bsum[blockIdx.x] = s[255];
}

__global__ void col_scan2(unsigned* __restrict__ bsum){   // 196 partials, 1 block
  __shared__ unsigned s[256];
  int t = threadIdx.x;
  unsigned v = (t < 196) ? bsum[t] : 0u;
  s[t] = v;
  __syncthreads();
  for (int o = 1; o < 256; o <<= 1){
    unsigned u = (t >= o) ? s[t - o] : 0u;
    __syncthreads();
    s[t] += u;
    __syncthreads();
  }
  if (t < 196) bsum[t] = s[t] - v;    // exclusive block offsets
}

__global__ void col_scan3(unsigned* __restrict__ cpre, const unsigned* __restrict__ bsum){
  int i = blockIdx.x * 256 + threadIdx.x;
  cpre[i] += bsum[blockIdx.x];
}

// emeta[pos] = (col, row, seg, orig_edge); cpre used as cursors (destructive)
__global__ void col_scatter(const int* __restrict__ ei, const int* __restrict__ batch,
                            unsigned* __restrict__ cpre, int4* __restrict__ emeta){
  for (int i = 0; i < 4; i++){
    int e = blockIdx.x * 1024 + i * 256 + threadIdx.x;
    if (e < EDGES){
      int cn = ei[e];
      int pos = (int)atomicAdd(&cpre[cn], 1u);
      emeta[pos] = make_int4(cn, ei[EDGES + e], batch[cn], e);
    }
  }
}

// ---------------- node GEMM: P[node][512] = emb @ [W1top | W1bot] ----------------
__global__ __launch_bounds__(256) void node_gemm(
    const unsigned short* __restrict__ emb_bf, const unsigned short* __restrict__ w1tn,
    unsigned short* __restrict__ P)
{
  __shared__ unsigned short As[64 * 72];   // 64 nodes x 64 k, +8 pad
  int t = threadIdx.x;
  int n0 = blockIdx.x * 64;
  {
    int nl = t >> 2, part = t & 3;
    int node = n0 + nl; if (node >= NNODES) node = 0;
    const int4* src = (const int4*)(emb_bf + node * 64 + part * 16);
    int4* dst = (int4*)(As + nl * 72 + part * 16);
    dst[0] = src[0]; dst[1] = src[1];
  }
  __syncthreads();
  int w = t >> 6, lane = t & 63, q = lane >> 4, c = lane & 15;
  f32x4 acc[4][8];
  for (int a = 0; a < 4; a++) for (int b = 0; b < 8; b++) for (int r = 0; r < 4; r++) acc[a][b][r] = 0.f;
  for (int k0 = 0; k0 < 64; k0 += 32){
    bf16x8 af[4];
    for (int tt = 0; tt < 4; tt++) af[tt] = *(const bf16x8*)(As + (tt * 16 + c) * 72 + k0 + q * 8);
    for (int n4 = 0; n4 < 8; n4++){
      bf16x8 bw = *(const bf16x8*)(w1tn + (w * 128 + n4 * 16 + c) * 64 + k0 + q * 8);
      for (int tt = 0; tt < 4; tt++)
        acc[tt][n4] = __builtin_amdgcn_mfma_f32_16x16x32_bf16(af[tt], bw, acc[tt][n4], 0, 0, 0);
    }
  }
  for (int tt = 0; tt < 4; tt++){
    for (int r = 0; r < 4; r++){
      int node = n0 + tt * 16 + q * 4 + r;
      if (node < NNODES){
        unsigned short* dst = P + (size_t)node * 512 + w * 128 + c;
        for (int n4 = 0; n4 < 8; n4++) dst[n4 * 16] = f2bf(acc[tt][n4][r]);
      }
    }
  }
}

// ---------------- K1: gather + segmented stats1 (depth-4 rolling prefetch) ----------------
__global__ __launch_bounds__(256) void k1_gather(
    const unsigned short* __restrict__ P, const int4* __restrict__ emeta,
    float* __restrict__ sum1, float* __restrict__ sqs1)
{
  int lane = threadIdx.x & 63;
  int bid = xcd_swizzle(blockIdx.x, gridDim.x);
  int wid = (bid * 256 + threadIdx.x) >> 6;
  if (wid >= NTILES) return;
  int p0 = wid * 64;
  int4 me = emeta[p0 + lane];
  int c4 = lane * 4;
  int s0 = __builtin_amdgcn_readlane(me.z, 0);
  bool uni = (__ballot(me.z == s0) == ~0ull);
  float sm0 = 0.f, sm1 = 0.f, sm2 = 0.f, sm3 = 0.f;
  float q0 = 0.f, q1 = 0.f, q2 = 0.f, q3 = 0.f;
  if (uni){
    int cprev = __builtin_amdgcn_readlane(me.x, 0);
    ushort4 a = *(const ushort4*)(P + (size_t)cprev * 512 + c4);
    ushort4 cur[4];
    #pragma unroll
    for (int j = 0; j < 4; j++){
      int re = __builtin_amdgcn_readlane(me.y, j);
      cur[j] = *(const ushort4*)(P + (size_t)re * 512 + 256 + c4);
    }
    for (int eb = 0; eb < 64; eb += 4){
      ushort4 nxt[4];
      if (eb < 60){
        #pragma unroll
        for (int j = 0; j < 4; j++){
          int re = __builtin_amdgcn_readlane(me.y, eb + 4 + j);
          nxt[j] = *(const ushort4*)(P + (size_t)re * 512 + 256 + c4);
        }
      }
      #pragma unroll
      for (int j = 0; j < 4; j++){
        int ce = __builtin_amdgcn_readlane(me.x, eb + j);
        if (ce != cprev){ a = *(const ushort4*)(P + (size_t)ce * 512 + c4); cprev = ce; }
        float x0 = bf2f(a.x) + bf2f(cur[j].x);
        float x1 = bf2f(a.y) + bf2f(cur[j].y);
        float x2v = bf2f(a.z) + bf2f(cur[j].z);
        float x3 = bf2f(a.w) + bf2f(cur[j].w);
        sm0 += x0; q0 += x0 * x0;
        sm1 += x1; q1 += x1 * x1;
        sm2 += x2v; q2 += x2v * x2v;
        sm3 += x3; q3 += x3 * x3;
      }
      #pragma unroll
      for (int j = 0; j < 4; j++) cur[j] = nxt[j];
    }
    float* sp = sum1 + s0 * 256 + c4;
    float* qp = sqs1 + s0 * 256 + c4;
    atomicAdd(sp + 0, sm0); atomicAdd(sp + 1, sm1); atomicAdd(sp + 2, sm2); atomicAdd(sp + 3, sm3);
    atomicAdd(qp + 0, q0);  atomicAdd(qp + 1, q1);  atomicAdd(qp + 2, q2);  atomicAdd(qp + 3, q3);
  } else {
    int cur = s0;
    int cprev = -1;
    ushort4 a = make_ushort4(0,0,0,0);
    for (int e = 0; e < 64; e++){
      int ce = __builtin_amdgcn_readlane(me.x, e);
      int re = __builtin_amdgcn_readlane(me.y, e);
      if (ce != cprev){ a = *(const ushort4*)(P + (size_t)ce * 512 + c4); cprev = ce; }
      ushort4 b = *(const ushort4*)(P + (size_t)re * 512 + 256 + c4);
      int s = __builtin_amdgcn_readlane(me.z, e);
      if (s != cur){
        float* sp = sum1 + cur * 256 + c4;
        float* qp = sqs1 + cur * 256 + c4;
        atomicAdd(sp + 0, sm0); atomicAdd(sp + 1, sm1); atomicAdd(sp + 2, sm2); atomicAdd(sp + 3, sm3);
        atomicAdd(qp + 0, q0);  atomicAdd(qp + 1, q1);  atomicAdd(qp + 2, q2);  atomicAdd(qp + 3, q3);
        sm0 = sm1 = sm2 = sm3 = 0.f; q0 = q1 = q2 = q3 = 0.f;
        cur = s;
      }
      float x0 = bf2f(a.x) + bf2f(b.x);
      float x1 = bf2f(a.y) + bf2f(b.y);
      float x2v = bf2f(a.z) + bf2f(b.z);
      float x3 = bf2f(a.w) + bf2f(b.w);
      sm0 += x0; q0 += x0 * x0;
      sm1 += x1; q1 += x1 * x1;
      sm2 += x2v; q2 += x2v * x2v;
      sm3 += x3; q3 += x3 * x3;
    }
    float* sp = sum1 + cur * 256 + c4;
    float* qp = sqs1 + cur * 256 + c4;
    atomicAdd(sp + 0, sm0); atomicAdd(sp + 1, sm1); atomicAdd(sp + 2, sm2); atomicAdd(sp + 3, sm3);
    atomicAdd(qp + 0, q0);  atomicAdd(qp + 1, q1);  atomicAdd(qp + 2, q2);  atomicAdd(qp + 3, q3);
  }
}

// ---------------- finalize: emit rstd and mean*rstd ----------------
__global__ void finalize1(const float* __restrict__ sum1, const float* __restrict__ sqs1,
                          const unsigned* __restrict__ hist, float* __restrict__ r1,
                          float* __restrict__ mr1){
  int i = blockIdx.x * 256 + threadIdx.x;   // 512*256
  int g = i >> 8;
  float cnt = fmaxf((float)hist[g], 1.f);
  float m = sum1[i] / cnt;
  float v = sqs1[i] / cnt - m * m;
  v = fmaxf(v, 0.f);
  float r = rsqrtf(v + 1e-5f);
  r1[i] = r;
  mr1[i] = m * r;
}

__global__ void finalize2(const float* __restrict__ sum2, const float* __restrict__ sqs2,
                          const unsigned* __restrict__ hist, float* __restrict__ r2,
                          float* __restrict__ mr2){
  int i = blockIdx.x * 256 + threadIdx.x;   // 512*64
  int g = i >> 6;
  float cnt = fmaxf((float)hist[g], 1.f);
  float m = sum2[i] / cnt;
  float v = sqs2[i] / cnt - m * m;
  v = fmaxf(v, 0.f);
  float r = rsqrtf(v + 1e-5f);
  r2[i] = r;
  mr2[i] = m * r;
}

// ---------------- K2: gather -> norm/relu -> GEMM2 + stats2 + x2T store ----------------
__global__ __launch_bounds__(256) void k2_fused(
    const unsigned short* __restrict__ P, const unsigned short* __restrict__ w2t,
    const int4* __restrict__ emeta,
    const float* __restrict__ r1, const float* __restrict__ mr1,
    float* __restrict__ sum2, float* __restrict__ sqs2,
    unsigned short* __restrict__ x2t)
{
  __shared__ unsigned short Y[64 * 264];   // y1 tile, [edge][256ch] +8 pad
  __shared__ int segl[64];
  __shared__ short rsegA[64];
  __shared__ unsigned char rloA[65];
  __shared__ int nrunS;
  int t = threadIdx.x;
  int bid = xcd_swizzle(blockIdx.x, gridDim.x);
  int p0 = bid * 64;
  int w = t >> 6, lane = t & 63, q = lane >> 4, c = lane & 15;
  int c4 = lane * 4;
  int elb0 = w * 16;
  int4 me = emeta[p0 + elb0 + (lane & 15)];

  // deep prefetch: 16 outstanding row loads (k2 is LDS-occupancy-capped; VGPRs are free here)
  ushort4 bb[16];
  #pragma unroll
  for (int e = 0; e < 16; e++){
    int re = __builtin_amdgcn_readlane(me.y, e);
    bb[e] = *(const ushort4*)(P + (size_t)re * 512 + 256 + c4);
  }
  int cprev = __builtin_amdgcn_readlane(me.x, 0);
  ushort4 a = *(const ushort4*)(P + (size_t)cprev * 512 + c4);
  int s0g = __builtin_amdgcn_readlane(me.z, 0);
  float4 r4  = *(const float4*)(r1  + s0g * 256 + c4);
  float4 mr4 = *(const float4*)(mr1 + s0g * 256 + c4);

  if (t < 64) segl[t] = emeta[p0 + t].z;
  if (w == 0){
    int sN = segl[lane];
    int nxt = (lane < 63) ? segl[lane + 1] : sN;
    unsigned long long mask = __ballot(sN != nxt);
    if (lane == 0){
      if (mask == 0ull){
        nrunS = 1; rloA[0] = 0; rloA[1] = 64; rsegA[0] = (short)sN;
      } else {
        int n = 0, cur = segl[0];
        rsegA[0] = (short)cur; rloA[0] = 0;
        for (int i = 1; i < 64; i++)
          if (segl[i] != cur){ cur = segl[i]; n++; rsegA[n] = (short)cur; rloA[n] = (unsigned char)i; }
        rloA[n + 1] = 64; nrunS = n + 1;
      }
    }
  }
  __syncthreads();
  int nrun = nrunS;
  bool uni = (nrun == 1);

  #pragma unroll
  for (int e = 0; e < 16; e++){
    int ce = __builtin_amdgcn_readlane(me.x, e);
    if (ce != cprev){ a = *(const ushort4*)(P + (size_t)ce * 512 + c4); cprev = ce; }
    float4 rr4 = r4, mm4 = mr4;
    if (!uni){
      int s = __builtin_amdgcn_readlane(me.z, e);
      rr4 = *(const float4*)(r1  + s * 256 + c4);
      mm4 = *(const float4*)(mr1 + s * 256 + c4);
    }
    float y0 = fmaxf(0.f, (bf2f(a.x) + bf2f(bb[e].x)) * rr4.x - mm4.x);
    float y1 = fmaxf(0.f, (bf2f(a.y) + bf2f(bb[e].y)) * rr4.y - mm4.y);
    float y2 = fmaxf(0.f, (bf2f(a.z) + bf2f(bb[e].z)) * rr4.z - mm4.z);
    float y3 = fmaxf(0.f, (bf2f(a.w) + bf2f(bb[e].w)) * rr4.w - mm4.w);
    uint2 pk;
    pk.x = pk2bf(y0, y1);
    pk.y = pk2bf(y2, y3);
    *(uint2*)(Y + (elb0 + e) * 264 + c4) = pk;
  }
  __syncthreads();

  // GEMM2: wave w owns out-channels [w*16, w*16+16)
  f32x4 acc2[4];
  for (int tt = 0; tt < 4; tt++) for (int r = 0; r < 4; r++) acc2[tt][r] = 0.f;
  int ch2 = w * 16 + c;
  for (int kc = 0; kc < 8; kc++){
    int k0 = kc * 32;
    bf16x8 bfr = *(const bf16x8*)(w2t + ch2 * 256 + k0 + q * 8);
    for (int tt = 0; tt < 4; tt++){
      bf16x8 afr = *(const bf16x8*)(Y + (tt * 16 + c) * 264 + k0 + q * 8);
      acc2[tt] = __builtin_amdgcn_mfma_f32_16x16x32_bf16(afr, bfr, acc2[tt], 0, 0, 0);
    }
  }

  if (uni){
    int s = segl[0];
    float sm = 0.f, sq = 0.f;
    for (int tt = 0; tt < 4; tt++)
      for (int r = 0; r < 4; r++){
        float v = acc2[tt][r];
        sm += v; sq += v * v;
      }
    sm += __shfl_xor(sm, 16); sq += __shfl_xor(sq, 16);
    sm += __shfl_xor(sm, 32); sq += __shfl_xor(sq, 32);
    if (q == 0){
      atomicAdd(&sum2[s * 64 + ch2], sm);
      atomicAdd(&sqs2[s * 64 + ch2], sq);
    }
  } else {
    for (int rr = 0; rr < nrun; rr++){
      int s = rsegA[rr], lo = rloA[rr], hi = rloA[rr + 1];
      float sm = 0.f, sq = 0.f;
      for (int tt = 0; tt < 4; tt++){
        int elb = tt * 16 + q * 4;
        for (int r = 0; r < 4; r++){
          int el = elb + r;
          if (el >= lo && el < hi){
            float v = acc2[tt][r];
            sm += v; sq += v * v;
          }
        }
      }
      sm += __shfl_xor(sm, 16); sq += __shfl_xor(sq, 16);
      sm += __shfl_xor(sm, 32); sq += __shfl_xor(sq, 32);
      if (q == 0){
        atomicAdd(&sum2[s * 64 + ch2], sm);
        atomicAdd(&sqs2[s * 64 + ch2], sq);
      }
    }
  }
  // x2T store: [ch][edge], ushort4 over 4 consecutive edges
  for (int tt = 0; tt < 4; tt++){
    uint2 pk;
    pk.x = pk2bf(acc2[tt][0], acc2[tt][1]);
    pk.y = pk2bf(acc2[tt][2], acc2[tt][3]);
    *(uint2*)(x2t + (size_t)ch2 * EDGES + p0 + tt * 16 + q * 4) = pk;
  }
}

// ---------------- K3: normalize2 + GEMV W3, 4 edges/thread (x2t is [ch][edge]) ----------------
__global__ __launch_bounds__(256) void k3_out(
    const unsigned short* __restrict__ x2t, const int4* __restrict__ emeta,
    const float* __restrict__ r2, const float* __restrict__ mr2,
    const float* __restrict__ W3, const float* __restrict__ b3, float* __restrict__ out)
{
  int pp4 = (blockIdx.x * 256 + threadIdx.x) * 4;
  if (pp4 >= EDGES) return;
  int4 m0 = emeta[pp4 + 0];
  int4 m1 = emeta[pp4 + 1];
  int4 m2 = emeta[pp4 + 2];
  int4 m3 = emeta[pp4 + 3];
  float a0 = 0.f, a1 = 0.f, a2 = 0.f, a3 = 0.f;
  if (m0.z == m3.z && m0.z == m1.z && m0.z == m2.z){
    const float* rp = r2  + m0.z * 64;
    const float* mp = mr2 + m0.z * 64;
    #pragma unroll 8
    for (int ch = 0; ch < 64; ch++){
      ushort4 v = *(const ushort4*)(x2t + (size_t)ch * EDGES + pp4);
      float rr = rp[ch], mm = mp[ch], wv = W3[ch];
      a0 += fmaxf(0.f, bf2f(v.x) * rr - mm) * wv;
      a1 += fmaxf(0.f, bf2f(v.y) * rr - mm) * wv;
      a2 += fmaxf(0.f, bf2f(v.z) * rr - mm) * wv;
      a3 += fmaxf(0.f, bf2f(v.w) * rr - mm) * wv;
    }
  } else {
    #pragma unroll 8
    for (int ch = 0; ch < 64; ch++){
      ushort4 v = *(const ushort4*)(x2t + (size_t)ch * EDGES + pp4);
      float wv = W3[ch];
      a0 += fmaxf(0.f, bf2f(v.x) * r2[m0.z * 64 + ch] - mr2[m0.z * 64 + ch]) * wv;
      a1 += fmaxf(0.f, bf2f(v.y) * r2[m1.z * 64 + ch] - mr2[m1.z * 64 + ch]) * wv;
      a2 += fmaxf(0.f, bf2f(v.z) * r2[m2.z * 64 + ch] - mr2[m2.z * 64 + ch]) * wv;
      a3 += fmaxf(0.f, bf2f(v.w) * r2[m3.z * 64 + ch] - mr2[m3.z * 64 + ch]) * wv;
    }
  }
  float bv = b3[0];
  out[m0.w] = a0 + bv;
  out[m1.w] = a1 + bv;
  out[m2.w] = a2 + bv;
  out[m3.w] = a3 + bv;
}

// ---------------- launch ----------------
extern "C" void kernel_launch(void* const* d_in, const int* in_sizes, int n_in,
                              void* d_out, int out_size, void* d_ws, size_t ws_size,
                              hipStream_t stream)
{
  (void)in_sizes; (void)n_in; (void)out_size;
  const float* emb = (const float*)d_in[0];
  const float* W1  = (const float*)d_in[1];
  const float* W2  = (const float*)d_in[3];
  const float* W3  = (const float*)d_in[5];
  const float* b3  = (const float*)d_in[6];
  const int* ei    = (const int*)d_in[7];
  const int* batch = (const int*)d_in[8];
  float* out = (float*)d_out;

  char* p = (char*)d_ws;
  size_t off = 0;
  auto take = [&](size_t n) -> char* {
    char* r = p + off;
    off += (n + 255) & ~(size_t)255;
    return r;
  };

  unsigned short* emb_bf = (unsigned short*)take((size_t)NNODES * 64 * 2);
  unsigned short* w1tn   = (unsigned short*)take(32768 * 2);
  unsigned short* w2t    = (unsigned short*)take(16384 * 2);
  int4* emeta = (int4*)take((size_t)EDGES * 16);
  unsigned short* P   = (unsigned short*)take((size_t)NNODES * 512 * 2);
  unsigned short* x2t = (unsigned short*)take((size_t)EDGES * 64 * 2);
  float* r1  = (float*)take(512 * 256 * 4);
  float* mr1 = (float*)take(512 * 256 * 4);
  float* r2  = (float*)take(512 * 64 * 4);
  float* mr2 = (float*)take(512 * 64 * 4);
  unsigned* cpre = (unsigned*)take(NCOLB * 4);
  unsigned* bsum = (unsigned*)take(256 * 4);
  // zero-init region (contiguous)
  char* zbase = p + off;
  unsigned* hist  = (unsigned*)take(NG * 4);
  unsigned* chist = (unsigned*)take(NCOLB * 4);
  float* sum1 = (float*)take(512 * 256 * 4);
  float* sqs1 = (float*)take(512 * 256 * 4);
  float* sum2 = (float*)take(512 * 64 * 4);
  float* sqs2 = (float*)take(512 * 64 * 4);
  size_t zsize = (size_t)((p + off) - zbase);

  if (ws_size < off) return;  // workspace too small — fail loudly via poison

  hipMemsetAsync(zbase, 0, zsize, stream);
  prep_all<<<12692, 256, 0, stream>>>(emb, W1, W2, emb_bf, w1tn, w2t);
  hists<<<977, 256, 0, stream>>>(ei, batch, hist, chist);
  col_scan1<<<196, 256, 0, stream>>>(chist, cpre, bsum);
  col_scan2<<<1, 256, 0, stream>>>(bsum);
  col_scan3<<<196, 256, 0, stream>>>(cpre, bsum);
  col_scatter<<<977, 256, 0, stream>>>(ei, batch, cpre, emeta);
  node_gemm<<<(NNODES + 63) / 64, 256, 0, stream>>>(emb_bf, w1tn, P);
  k1_gather<<<(NTILES + 3) / 4, 256, 0, stream>>>(P, emeta, sum1, sqs1);
  finalize1<<<512, 256, 0, stream>>>(sum1, sqs1, hist, r1, mr1);
  k2_fused<<<NTILES, 256, 0, stream>>>(P, w2t, emeta, r1, mr1, sum2, sqs2, x2t);
  finalize2<<<128, 256, 0, stream>>>(sum2, sqs2, hist, r2, mr2);
  k3_out<<<977, 256, 0, stream>>>(x2t, emeta, r2, mr2, W3, b3, out);
}